// Round 2
// baseline (139.128 us; speedup 1.0000x reference)
//
#include <hip/hip_runtime.h>

#define Dq   256
#define ATTR 400
#define HW   3136
#define NB   32

// ---------------- Kernel A: per-batch count-sketch vector sk1[b][256] ----------------
__global__ __launch_bounds__(256) void k_sk1(
    const float* __restrict__ oh,      // [B,400]
    const float* __restrict__ W_emb,   // [256,400]
    const float* __restrict__ b_emb,   // [256]
    const float* __restrict__ conv_w,  // [256,256]
    const float* __restrict__ conv_b,  // [256]
    const int*   __restrict__ h1,      // [256]
    const float* __restrict__ s1,      // [256]
    float*       __restrict__ sk1_out) // [B,256]
{
  __shared__ float ohs[ATTR];
  __shared__ float ts[Dq];
  __shared__ float sk[Dq];
  const int b = blockIdx.x, tid = threadIdx.x;
  for (int j = tid; j < ATTR; j += 256) ohs[j] = oh[b * ATTR + j];
  sk[tid] = 0.f;
  __syncthreads();
  // t[i] = oh . W_emb[i,:] + b_emb[i]
  float acc = b_emb[tid];
  const float* wr = W_emb + tid * ATTR;
  for (int j = 0; j < ATTR; ++j) acc = fmaf(ohs[j], wr[j], acc);
  ts[tid] = acc;
  __syncthreads();
  // a[i] = t . conv_w[i,:] + conv_b[i]
  float a = conv_b[tid];
  const float* cr = conv_w + tid * Dq;
  for (int k = 0; k < Dq; ++k) a = fmaf(ts[k], cr[k], a);
  // sk1[d] += a[i]*s1[i] where h1[i]==d
  atomicAdd(&sk[h1[tid]], a * s1[tid]);
  __syncthreads();
  sk1_out[b * Dq + tid] = sk[tid];
}

// ---------------- Kernel B: fold conv1 through circular conv -> G[b][c][o] ----------------
__global__ __launch_bounds__(256) void k_G(
    const float* __restrict__ sk1,     // [B,256]
    const float* __restrict__ conv1_w, // [32,256]
    const int*   __restrict__ h2,      // [256]
    const float* __restrict__ s2,      // [256]
    float*       __restrict__ G)       // [B,256(c),32(o)]
{
  __shared__ float sks[Dq];
  __shared__ float w1[Dq];
  __shared__ float Tl[Dq];
  const int b = blockIdx.x >> 5, o = blockIdx.x & 31, tid = threadIdx.x;
  sks[tid] = sk1[b * Dq + tid];
  w1[tid]  = conv1_w[o * Dq + tid];
  __syncthreads();
  // T[o,j] = sum_d conv1_w[o,d] * sk1[(d-j) mod 256]
  float t = 0.f;
  for (int d = 0; d < Dq; ++d) t = fmaf(w1[d], sks[(d - tid) & 255], t);
  Tl[tid] = t;
  __syncthreads();
  // G[b,c,o] = s2[c] * T[o,h2[c]]
  G[(b * Dq + tid) * 32 + o] = s2[tid] * Tl[h2[tid]];
}

// ---------------- Kernel C: main streaming pass over pixels ----------------
__global__ __launch_bounds__(256) void k_main(
    const float* __restrict__ ent,     // [B,256,HW]
    const float* __restrict__ G,       // [B,256,32]
    const float* __restrict__ c1b,     // [32]
    const float* __restrict__ c2w,     // [32]
    const float* __restrict__ c2b,     // [1]
    float*       __restrict__ out)     // attr_map [B*HW] then attr_feature [B*256*HW]
{
  __shared__ float Gs[Dq * 32];  // 32 KB, [c][o]
  const int b = blockIdx.y, tid = threadIdx.x;
  const float* Gb = G + (size_t)b * (Dq * 32);
  for (int i = tid; i < Dq * 32; i += 256) Gs[i] = Gb[i];
  __syncthreads();
  const int p = blockIdx.x * 256 + tid;   // pixel index within batch
  if (p >= HW) return;
  const float* ep = ent + (size_t)b * (Dq * HW) + p;

  float a[32];
#pragma unroll
  for (int o = 0; o < 32; ++o) a[o] = 0.f;

#pragma unroll 2
  for (int c = 0; c < Dq; ++c) {
    float f = fmaxf(ep[(size_t)c * HW], 0.f);
    const float4* g4 = reinterpret_cast<const float4*>(&Gs[c * 32]);
#pragma unroll
    for (int k = 0; k < 8; ++k) {
      float4 g = g4[k];
      a[4 * k + 0] = fmaf(g.x, f, a[4 * k + 0]);
      a[4 * k + 1] = fmaf(g.y, f, a[4 * k + 1]);
      a[4 * k + 2] = fmaf(g.z, f, a[4 * k + 2]);
      a[4 * k + 3] = fmaf(g.w, f, a[4 * k + 3]);
    }
  }

  float z = c2b[0];
#pragma unroll
  for (int o = 0; o < 32; ++o)
    z = fmaf(c2w[o], fmaxf(a[o] + c1b[o], 0.f), z);
  float s = 1.f / (1.f + __expf(-z));

  // attr_map
  out[(size_t)b * HW + p] = s;

  // attr_feature = attr_map * entity  (raw entity, no relu); non-temporal
  // stores keep L2/L3 space for the entity re-read.
  float* feat = out + (size_t)NB * HW + (size_t)b * (Dq * HW) + p;
#pragma unroll 2
  for (int c = 0; c < Dq; ++c) {
    __builtin_nontemporal_store(s * ep[(size_t)c * HW], &feat[(size_t)c * HW]);
  }
}

extern "C" void kernel_launch(void* const* d_in, const int* in_sizes, int n_in,
                              void* d_out, int out_size, void* d_ws, size_t ws_size,
                              hipStream_t stream) {
  const float* ent    = (const float*)d_in[0];
  const float* oh     = (const float*)d_in[1];
  const float* W_emb  = (const float*)d_in[2];
  const float* b_emb  = (const float*)d_in[3];
  const float* conv_w = (const float*)d_in[4];
  const float* conv_b = (const float*)d_in[5];
  const float* c1w    = (const float*)d_in[6];
  const float* c1b    = (const float*)d_in[7];
  const float* c2w    = (const float*)d_in[8];
  const float* c2b    = (const float*)d_in[9];
  const int*   h1     = (const int*)d_in[10];
  const int*   h2     = (const int*)d_in[11];
  const float* s1     = (const float*)d_in[12];
  const float* s2     = (const float*)d_in[13];

  float* ws  = (float*)d_ws;
  float* sk1 = ws;            // 32*256 floats
  float* G   = ws + NB * Dq;  // 32*256*32 floats

  hipLaunchKernelGGL(k_sk1, dim3(NB), dim3(256), 0, stream,
                     oh, W_emb, b_emb, conv_w, conv_b, h1, s1, sk1);
  hipLaunchKernelGGL(k_G, dim3(NB * 32), dim3(256), 0, stream,
                     sk1, c1w, h2, s2, G);
  hipLaunchKernelGGL(k_main, dim3((HW + 255) / 256, NB), dim3(256), 0, stream,
                     ent, G, c1b, c2w, c2b, (float*)d_out);
}

// Round 3
// 124.095 us; speedup vs baseline: 1.1211x; 1.1211x over previous
//
#include <hip/hip_runtime.h>

#define Dq   256
#define ATTR 400
#define HW   3136
#define NB   32

// ---------------- Kernel A: per-batch count-sketch vector sk1[b][256] ----------------
__global__ __launch_bounds__(256) void k_sk1(
    const float* __restrict__ oh,      // [B,400]
    const float* __restrict__ W_emb,   // [256,400]
    const float* __restrict__ b_emb,   // [256]
    const float* __restrict__ conv_w,  // [256,256]
    const float* __restrict__ conv_b,  // [256]
    const int*   __restrict__ h1,      // [256]
    const float* __restrict__ s1,      // [256]
    float*       __restrict__ sk1_out) // [B,256]
{
  __shared__ float ohs[ATTR];
  __shared__ float ts[Dq];
  __shared__ float sk[Dq];
  const int b = blockIdx.x, tid = threadIdx.x;
  for (int j = tid; j < ATTR; j += 256) ohs[j] = oh[b * ATTR + j];
  sk[tid] = 0.f;
  __syncthreads();
  float acc = b_emb[tid];
  const float* wr = W_emb + tid * ATTR;
  for (int j = 0; j < ATTR; ++j) acc = fmaf(ohs[j], wr[j], acc);
  ts[tid] = acc;
  __syncthreads();
  float a = conv_b[tid];
  const float* cr = conv_w + tid * Dq;
  for (int k = 0; k < Dq; ++k) a = fmaf(ts[k], cr[k], a);
  atomicAdd(&sk[h1[tid]], a * s1[tid]);
  __syncthreads();
  sk1_out[b * Dq + tid] = sk[tid];
}

// ---------------- Kernel B: fold conv1 through circular conv -> G[b][c][o] ----------------
__global__ __launch_bounds__(256) void k_G(
    const float* __restrict__ sk1,     // [B,256]
    const float* __restrict__ conv1_w, // [32,256]
    const int*   __restrict__ h2,      // [256]
    const float* __restrict__ s2,      // [256]
    float*       __restrict__ G)       // [B,256(c),32(o)]
{
  __shared__ float sks[Dq];
  __shared__ float w1[Dq];
  __shared__ float Tl[Dq];
  const int b = blockIdx.x >> 5, o = blockIdx.x & 31, tid = threadIdx.x;
  sks[tid] = sk1[b * Dq + tid];
  w1[tid]  = conv1_w[o * Dq + tid];
  __syncthreads();
  float t = 0.f;
  for (int d = 0; d < Dq; ++d) t = fmaf(w1[d], sks[(d - tid) & 255], t);
  Tl[tid] = t;
  __syncthreads();
  G[(b * Dq + tid) * 32 + o] = s2[tid] * Tl[h2[tid]];
}

// ---------------- Kernel C: main streaming pass ----------------
// Block = 256 threads = 4 channel-groups x 64 pixels. Each thread: 64
// channels of 1 pixel. LDS reduce across groups, then coalesced store pass.
__global__ __launch_bounds__(256) void k_main(
    const float* __restrict__ ent,     // [B,256,HW]
    const float* __restrict__ G,       // [B,256,32]
    const float* __restrict__ c1b,     // [32]
    const float* __restrict__ c2w,     // [32]
    const float* __restrict__ c2b,     // [1]
    float*       __restrict__ out)     // attr_map [B*HW] then attr_feature [B*256*HW]
{
  __shared__ float smem[8192];   // 32 KB: G[c][o] during main loop, then red[cg][o][pix]
  __shared__ float zp[4][64];
  __shared__ float sv[64];
  const int b = blockIdx.y, tid = threadIdx.x;
  const int pix = tid & 63, cg = tid >> 6;
  const int p = blockIdx.x * 64 + pix;

  const float* Gb = G + (size_t)b * 8192;
  for (int i = tid; i < 8192; i += 256) smem[i] = Gb[i];
  __syncthreads();

  const float* ep = ent + ((size_t)b * Dq + cg * 64) * HW + p;

  float a[32];
#pragma unroll
  for (int o = 0; o < 32; ++o) a[o] = 0.f;

#pragma unroll 4
  for (int cc = 0; cc < 64; ++cc) {
    float f = fmaxf(ep[(size_t)cc * HW], 0.f);
    const float4* g4 = reinterpret_cast<const float4*>(&smem[(cg * 64 + cc) * 32]);
#pragma unroll
    for (int k = 0; k < 8; ++k) {
      float4 g = g4[k];
      a[4 * k + 0] = fmaf(g.x, f, a[4 * k + 0]);
      a[4 * k + 1] = fmaf(g.y, f, a[4 * k + 1]);
      a[4 * k + 2] = fmaf(g.z, f, a[4 * k + 2]);
      a[4 * k + 3] = fmaf(g.w, f, a[4 * k + 3]);
    }
  }
  __syncthreads();  // done reading G from smem

  // red[cg][o][pix]: lanes write consecutive addresses -> conflict-free
#pragma unroll
  for (int o = 0; o < 32; ++o) smem[cg * 2048 + o * 64 + pix] = a[o];
  __syncthreads();

  // partial gate: this thread handles o in [8*cg, 8*cg+8) for its pixel
  float zpart = 0.f;
#pragma unroll
  for (int oo = 0; oo < 8; ++oo) {
    int o = cg * 8 + oo;
    float av = smem[0 * 2048 + o * 64 + pix] + smem[1 * 2048 + o * 64 + pix] +
               smem[2 * 2048 + o * 64 + pix] + smem[3 * 2048 + o * 64 + pix];
    zpart = fmaf(c2w[o], fmaxf(av + c1b[o], 0.f), zpart);
  }
  zp[cg][pix] = zpart;
  __syncthreads();

  if (tid < 64) {
    float z = c2b[0] + zp[0][tid] + zp[1][tid] + zp[2][tid] + zp[3][tid];
    float s = 1.f / (1.f + __expf(-z));
    sv[tid] = s;
    out[(size_t)b * HW + blockIdx.x * 64 + tid] = s;
  }
  __syncthreads();

  const float s = sv[pix];
  float* feat = out + (size_t)NB * HW + ((size_t)b * Dq + cg * 64) * HW + p;
#pragma unroll 4
  for (int cc = 0; cc < 64; ++cc) {
    __builtin_nontemporal_store(s * ep[(size_t)cc * HW], &feat[(size_t)cc * HW]);
  }
}

extern "C" void kernel_launch(void* const* d_in, const int* in_sizes, int n_in,
                              void* d_out, int out_size, void* d_ws, size_t ws_size,
                              hipStream_t stream) {
  const float* ent    = (const float*)d_in[0];
  const float* oh     = (const float*)d_in[1];
  const float* W_emb  = (const float*)d_in[2];
  const float* b_emb  = (const float*)d_in[3];
  const float* conv_w = (const float*)d_in[4];
  const float* conv_b = (const float*)d_in[5];
  const float* c1w    = (const float*)d_in[6];
  const float* c1b    = (const float*)d_in[7];
  const float* c2w    = (const float*)d_in[8];
  const float* c2b    = (const float*)d_in[9];
  const int*   h1     = (const int*)d_in[10];
  const int*   h2     = (const int*)d_in[11];
  const float* s1     = (const float*)d_in[12];
  const float* s2     = (const float*)d_in[13];

  float* ws  = (float*)d_ws;
  float* sk1 = ws;            // 32*256 floats
  float* G   = ws + NB * Dq;  // 32*256*32 floats

  hipLaunchKernelGGL(k_sk1, dim3(NB), dim3(256), 0, stream,
                     oh, W_emb, b_emb, conv_w, conv_b, h1, s1, sk1);
  hipLaunchKernelGGL(k_G, dim3(NB * 32), dim3(256), 0, stream,
                     sk1, c1w, h2, s2, G);
  hipLaunchKernelGGL(k_main, dim3(HW / 64, NB), dim3(256), 0, stream,
                     ent, G, c1b, c2w, c2b, (float*)d_out);
}

// Round 4
// 100.916 us; speedup vs baseline: 1.3787x; 1.2297x over previous
//
#include <hip/hip_runtime.h>

#define Dq   256
#define ATTR 400
#define HW   3136
#define NB   32

// ---------------- Kernel A: per-batch count-sketch vector sk1[b][256] ----------------
__global__ __launch_bounds__(256) void k_sk1(
    const float* __restrict__ oh,      // [B,400]
    const float* __restrict__ W_emb,   // [256,400]
    const float* __restrict__ b_emb,   // [256]
    const float* __restrict__ conv_w,  // [256,256]
    const float* __restrict__ conv_b,  // [256]
    const int*   __restrict__ h1,      // [256]
    const float* __restrict__ s1,      // [256]
    float*       __restrict__ sk1_out) // [B,256]
{
  __shared__ float ohs[ATTR];
  __shared__ float ts[Dq];
  __shared__ float sk[Dq];
  const int b = blockIdx.x, tid = threadIdx.x;
  for (int j = tid; j < ATTR; j += 256) ohs[j] = oh[b * ATTR + j];
  sk[tid] = 0.f;
  __syncthreads();
  float acc = b_emb[tid];
  const float* wr = W_emb + tid * ATTR;
  for (int j = 0; j < ATTR; ++j) acc = fmaf(ohs[j], wr[j], acc);
  ts[tid] = acc;
  __syncthreads();
  float a = conv_b[tid];
  const float* cr = conv_w + tid * Dq;
  for (int k = 0; k < Dq; ++k) a = fmaf(ts[k], cr[k], a);
  atomicAdd(&sk[h1[tid]], a * s1[tid]);
  __syncthreads();
  sk1_out[b * Dq + tid] = sk[tid];
}

// ---------------- Kernel B: fold conv1 through circular conv -> G[b][c][o] ----------------
__global__ __launch_bounds__(256) void k_G(
    const float* __restrict__ sk1,     // [B,256]
    const float* __restrict__ conv1_w, // [32,256]
    const int*   __restrict__ h2,      // [256]
    const float* __restrict__ s2,      // [256]
    float*       __restrict__ G)       // [B,256(c),32(o)]
{
  __shared__ float sks[Dq];
  __shared__ float w1[Dq];
  __shared__ float Tl[Dq];
  const int b = blockIdx.x >> 5, o = blockIdx.x & 31, tid = threadIdx.x;
  sks[tid] = sk1[b * Dq + tid];
  w1[tid]  = conv1_w[o * Dq + tid];
  __syncthreads();
  float t = 0.f;
  for (int d = 0; d < Dq; ++d) t = fmaf(w1[d], sks[(d - tid) & 255], t);
  Tl[tid] = t;
  __syncthreads();
  G[(b * Dq + tid) * 32 + o] = s2[tid] * Tl[h2[tid]];
}

__device__ __forceinline__ float4 relu4(float4 v) {
  return make_float4(fmaxf(v.x, 0.f), fmaxf(v.y, 0.f), fmaxf(v.z, 0.f), fmaxf(v.w, 0.f));
}

// ---------------- Kernel C: main streaming pass ----------------
// Block = 256 threads = 4 channel-groups x 64 lanes; each lane owns a float4
// of 4 consecutive pixels (coalesced 16B/lane). The 8 ds_read_b128 per
// channel iteration now feed 128 FMAs (4x amortization vs round 3).
__global__ __launch_bounds__(256, 2) void k_main(
    const float* __restrict__ ent,     // [B,256,HW]
    const float* __restrict__ G,       // [B,256,32]
    const float* __restrict__ c1b,     // [32]
    const float* __restrict__ c2w,     // [32]
    const float* __restrict__ c2b,     // [1]
    float*       __restrict__ out)     // attr_map [B*HW] then attr_feature [B*256*HW]
{
  __shared__ float smem[8192];   // 32 KB: G[c][o] during main loop, then red[cg][o][lane]
  __shared__ float zp[4][64];
  __shared__ float sv[64];
  const int b = blockIdx.y, tid = threadIdx.x;
  const int lane = tid & 63, cg = tid >> 6;
  const int p0 = blockIdx.x * 256 + lane * 4;   // first of this lane's 4 pixels
  const bool ok = p0 < HW;                      // p0 multiple of 4, HW multiple of 4

  const float* Gb = G + (size_t)b * 8192;
  for (int i = tid; i < 8192; i += 256) smem[i] = Gb[i];
  __syncthreads();

  const float* ep = ent + ((size_t)b * Dq + cg * 64) * HW + p0;

  float4 acc[32];
#pragma unroll
  for (int o = 0; o < 32; ++o) acc[o] = make_float4(0.f, 0.f, 0.f, 0.f);

#pragma unroll 2
  for (int cc = 0; cc < 64; ++cc) {
    float4 f = ok ? relu4(*reinterpret_cast<const float4*>(ep + (size_t)cc * HW))
                  : make_float4(0.f, 0.f, 0.f, 0.f);
    const float4* grow = reinterpret_cast<const float4*>(&smem[(cg * 64 + cc) * 32]);
#pragma unroll
    for (int k = 0; k < 8; ++k) {
      float4 g = grow[k];
#define FMA4(A, S) { (A).x = fmaf((S), f.x, (A).x); (A).y = fmaf((S), f.y, (A).y); \
                     (A).z = fmaf((S), f.z, (A).z); (A).w = fmaf((S), f.w, (A).w); }
      FMA4(acc[4 * k + 0], g.x);
      FMA4(acc[4 * k + 1], g.y);
      FMA4(acc[4 * k + 2], g.z);
      FMA4(acc[4 * k + 3], g.w);
    }
  }
  __syncthreads();  // G reads done; smem becomes reduction buffer

  // gate params for this thread's o-slice
  const int ob = cg * 8;
  float c1bv[8], c2wv[8];
#pragma unroll
  for (int oo = 0; oo < 8; ++oo) { c1bv[oo] = c1b[ob + oo]; c2wv[oo] = c2w[ob + oo]; }
  const float c2b0 = c2b[0];

  float sreg[4];
#pragma unroll
  for (int q = 0; q < 4; ++q) {
    // write component q (pixel lane*4+q) of each acc: red[cg][o][lane]
#pragma unroll
    for (int o = 0; o < 32; ++o) {
      float v = (q == 0) ? acc[o].x : (q == 1) ? acc[o].y : (q == 2) ? acc[o].z : acc[o].w;
      smem[cg * 2048 + o * 64 + lane] = v;
    }
    __syncthreads();
    float zpart = 0.f;
#pragma unroll
    for (int oo = 0; oo < 8; ++oo) {
      int o = ob + oo;
      float av = smem[0 * 2048 + o * 64 + lane] + smem[1 * 2048 + o * 64 + lane] +
                 smem[2 * 2048 + o * 64 + lane] + smem[3 * 2048 + o * 64 + lane];
      zpart = fmaf(c2wv[oo], fmaxf(av + c1bv[oo], 0.f), zpart);
    }
    zp[cg][lane] = zpart;
    __syncthreads();
    if (tid < 64) {
      float z = c2b0 + zp[0][tid] + zp[1][tid] + zp[2][tid] + zp[3][tid];
      sv[tid] = 1.f / (1.f + __expf(-z));
    }
    __syncthreads();
    sreg[q] = sv[lane];
  }

  // attr_map: one float4 per lane, from cg 0 only
  if (cg == 0 && ok) {
    float4 sm = make_float4(sreg[0], sreg[1], sreg[2], sreg[3]);
    *reinterpret_cast<float4*>(out + (size_t)b * HW + p0) = sm;
  }

  // attr_feature = s * entity (raw, no relu); entity re-read is L2-hot
  if (ok) {
    float* feat = out + (size_t)NB * HW + ((size_t)b * Dq + cg * 64) * HW + p0;
#pragma unroll 2
    for (int cc = 0; cc < 64; ++cc) {
      float4 e = *reinterpret_cast<const float4*>(ep + (size_t)cc * HW);
      float4 r = make_float4(e.x * sreg[0], e.y * sreg[1], e.z * sreg[2], e.w * sreg[3]);
      __builtin_nontemporal_store(r.x, feat + (size_t)cc * HW + 0);
      __builtin_nontemporal_store(r.y, feat + (size_t)cc * HW + 1);
      __builtin_nontemporal_store(r.z, feat + (size_t)cc * HW + 2);
      __builtin_nontemporal_store(r.w, feat + (size_t)cc * HW + 3);
    }
  }
}

extern "C" void kernel_launch(void* const* d_in, const int* in_sizes, int n_in,
                              void* d_out, int out_size, void* d_ws, size_t ws_size,
                              hipStream_t stream) {
  const float* ent    = (const float*)d_in[0];
  const float* oh     = (const float*)d_in[1];
  const float* W_emb  = (const float*)d_in[2];
  const float* b_emb  = (const float*)d_in[3];
  const float* conv_w = (const float*)d_in[4];
  const float* conv_b = (const float*)d_in[5];
  const float* c1w    = (const float*)d_in[6];
  const float* c1b    = (const float*)d_in[7];
  const float* c2w    = (const float*)d_in[8];
  const float* c2b    = (const float*)d_in[9];
  const int*   h1     = (const int*)d_in[10];
  const int*   h2     = (const int*)d_in[11];
  const float* s1     = (const float*)d_in[12];
  const float* s2     = (const float*)d_in[13];

  float* ws  = (float*)d_ws;
  float* sk1 = ws;            // 32*256 floats
  float* G   = ws + NB * Dq;  // 32*256*32 floats

  hipLaunchKernelGGL(k_sk1, dim3(NB), dim3(256), 0, stream,
                     oh, W_emb, b_emb, conv_w, conv_b, h1, s1, sk1);
  hipLaunchKernelGGL(k_G, dim3(NB * 32), dim3(256), 0, stream,
                     sk1, c1w, h2, s2, G);
  hipLaunchKernelGGL(k_main, dim3((HW + 255) / 256, NB), dim3(256), 0, stream,
                     ent, G, c1b, c2w, c2b, (float*)d_out);
}

// Round 6
// 86.420 us; speedup vs baseline: 1.6099x; 1.1677x over previous
//
#include <hip/hip_runtime.h>

#define Dq   256
#define ATTR 400
#define HW   3136
#define NB   32

typedef __attribute__((ext_vector_type(8))) short bf16x8;
typedef __attribute__((ext_vector_type(4))) float f32x4;

__device__ __forceinline__ unsigned short f2bf(float f) {
  unsigned int x = __float_as_uint(f);
  return (unsigned short)((x + 0x7FFFu + ((x >> 16) & 1u)) >> 16);
}

// ---------------- Kernel A: per-batch count-sketch vector sk1[b][256] ----------------
__global__ __launch_bounds__(256) void k_sk1(
    const float* __restrict__ oh, const float* __restrict__ W_emb,
    const float* __restrict__ b_emb, const float* __restrict__ conv_w,
    const float* __restrict__ conv_b, const int* __restrict__ h1,
    const float* __restrict__ s1, float* __restrict__ sk1_out) {
  __shared__ float ohs[ATTR];
  __shared__ float ts[Dq];
  __shared__ float sk[Dq];
  const int b = blockIdx.x, tid = threadIdx.x;
  for (int j = tid; j < ATTR; j += 256) ohs[j] = oh[b * ATTR + j];
  sk[tid] = 0.f;
  __syncthreads();
  float acc = b_emb[tid];
  const float* wr = W_emb + tid * ATTR;
  for (int j = 0; j < ATTR; ++j) acc = fmaf(ohs[j], wr[j], acc);
  ts[tid] = acc;
  __syncthreads();
  float a = conv_b[tid];
  const float* cr = conv_w + tid * Dq;
  for (int k = 0; k < Dq; ++k) a = fmaf(ts[k], cr[k], a);
  atomicAdd(&sk[h1[tid]], a * s1[tid]);
  __syncthreads();
  sk1_out[b * Dq + tid] = sk[tid];
}

// ---------------- Kernel B: G[b][c][o] = s2[c] * T[o, h2[c]] ----------------
__global__ __launch_bounds__(256) void k_G(
    const float* __restrict__ sk1, const float* __restrict__ conv1_w,
    const int* __restrict__ h2, const float* __restrict__ s2,
    float* __restrict__ G) {
  __shared__ float sks[Dq];
  __shared__ float w1[Dq];
  __shared__ float Tl[Dq];
  const int b = blockIdx.x >> 5, o = blockIdx.x & 31, tid = threadIdx.x;
  sks[tid] = sk1[b * Dq + tid];
  w1[tid]  = conv1_w[o * Dq + tid];
  __syncthreads();
  float t = 0.f;
  for (int d = 0; d < Dq; ++d) t = fmaf(w1[d], sks[(d - tid) & 255], t);
  Tl[tid] = t;
  __syncthreads();
  G[(b * Dq + tid) * 32 + o] = s2[tid] * Tl[h2[tid]];
}

// ---------------- Kernel A-pack: MFMA A-fragments Abuf[b][frag16][lane64][8] bf16 ----------------
// A[m=o][k=c] = G[c][o].  frag = tile*8 + ks; lane l elem j:
//   o = tile*16 + (l&15), c = ks*32 + (l>>4)*8 + j.
__global__ __launch_bounds__(256) void k_A(
    const float* __restrict__ G, unsigned short* __restrict__ Abuf) {
  const int b = blockIdx.x;
  const int l = threadIdx.x & 63, sub = threadIdx.x >> 6;
#pragma unroll
  for (int r = 0; r < 4; ++r) {
    const int frag = r * 4 + sub;
    const int tile = frag >> 3, ks = frag & 7;
    const int o = tile * 16 + (l & 15);
    unsigned short v[8];
#pragma unroll
    for (int j = 0; j < 8; ++j) {
      const int c = ks * 32 + (l >> 4) * 8 + j;
      v[j] = f2bf(G[((size_t)b * Dq + c) * 32 + o]);
    }
    unsigned short* dst = Abuf + (((size_t)b * 16 + frag) * 64 + l) * 8;
#pragma unroll
    for (int j = 0; j < 8; ++j) dst[j] = v[j];
  }
}

// ---------------- Kernel MAP: per-wave MFMA gate, zero LDS ----------------
// Wave handles 16 pixels x 256 channels. A (G^T, bf16) resident in 64 VGPRs.
__global__ __launch_bounds__(256, 4) void k_map(
    const float* __restrict__ ent,            // [B,256,HW]
    const unsigned short* __restrict__ Abuf,  // [B,16,64,8]
    const float* __restrict__ c1b, const float* __restrict__ c2w,
    const float* __restrict__ c2b,
    float* __restrict__ out_map)              // [B,HW]
{
  const int b = blockIdx.y;
  const int w = threadIdx.x >> 6, l = threadIdx.x & 63;
  const int px0 = (blockIdx.x * 4 + w) * 16;          // 49*4*16 = 3136 exact

  // load the 16 A-fragments (2 M-tiles x 8 K-steps), 16B per lane each
  bf16x8 A0[8], A1[8];
  const unsigned short* Ab = Abuf + ((size_t)b * 16 * 64 + l) * 8;
#pragma unroll
  for (int ks = 0; ks < 8; ++ks) {
    A0[ks] = *reinterpret_cast<const bf16x8*>(Ab + (size_t)(0 * 8 + ks) * 64 * 8);
    A1[ks] = *reinterpret_cast<const bf16x8*>(Ab + (size_t)(1 * 8 + ks) * 64 * 8);
  }

  f32x4 acc0 = {0.f, 0.f, 0.f, 0.f}, acc1 = {0.f, 0.f, 0.f, 0.f};
  const float* ep = ent + (size_t)b * Dq * HW + px0 + (l & 15);
  const int krow = (l >> 4) * 8;

#pragma unroll
  for (int ks = 0; ks < 8; ++ks) {
    float f[8];
#pragma unroll
    for (int j = 0; j < 8; ++j)
      f[j] = fmaxf(ep[(size_t)(ks * 32 + krow + j) * HW], 0.f);
    bf16x8 bv;
#pragma unroll
    for (int j = 0; j < 8; ++j) bv[j] = (short)f2bf(f[j]);
    acc0 = __builtin_amdgcn_mfma_f32_16x16x32_bf16(A0[ks], bv, acc0, 0, 0, 0);
    acc1 = __builtin_amdgcn_mfma_f32_16x16x32_bf16(A1[ks], bv, acc1, 0, 0, 0);
  }

  // epilogue: C/D layout col(px)=lane&15, row(o)=(lane>>4)*4+reg (+16 for tile1)
  const float4 b1a = reinterpret_cast<const float4*>(c1b)[l >> 4];
  const float4 b1b = reinterpret_cast<const float4*>(c1b)[(l >> 4) + 4];
  const float4 w2a = reinterpret_cast<const float4*>(c2w)[l >> 4];
  const float4 w2b = reinterpret_cast<const float4*>(c2w)[(l >> 4) + 4];
  float z = 0.f;
  z = fmaf(w2a.x, fmaxf(acc0[0] + b1a.x, 0.f), z);
  z = fmaf(w2a.y, fmaxf(acc0[1] + b1a.y, 0.f), z);
  z = fmaf(w2a.z, fmaxf(acc0[2] + b1a.z, 0.f), z);
  z = fmaf(w2a.w, fmaxf(acc0[3] + b1a.w, 0.f), z);
  z = fmaf(w2b.x, fmaxf(acc1[0] + b1b.x, 0.f), z);
  z = fmaf(w2b.y, fmaxf(acc1[1] + b1b.y, 0.f), z);
  z = fmaf(w2b.z, fmaxf(acc1[2] + b1b.z, 0.f), z);
  z = fmaf(w2b.w, fmaxf(acc1[3] + b1b.w, 0.f), z);
  z += __shfl_xor(z, 16);
  z += __shfl_xor(z, 32);
  const float s = 1.f / (1.f + __expf(-(z + c2b[0])));
  if (l < 16) out_map[(size_t)b * HW + px0 + l] = s;
}

// ---------------- Kernel MUL: streaming attr_feature = s * entity ----------------
__global__ __launch_bounds__(256) void k_mul(
    const float* __restrict__ ent, const float* __restrict__ map,
    float* __restrict__ out) {
  const int t = blockIdx.x * 256 + threadIdx.x;      // 3136*256 = 802816 threads
  const int p4 = t % 784;                            // HW/4
  const int rest = t / 784;
  const int cg = rest & 31, b = rest >> 5;
  const f32x4 s4 = *reinterpret_cast<const f32x4*>(map + (size_t)b * HW + p4 * 4);
  const float* ep = ent + ((size_t)b * Dq + cg * 8) * HW + p4 * 4;
  float* op = out + (size_t)NB * HW + ((size_t)b * Dq + cg * 8) * HW + p4 * 4;
#pragma unroll
  for (int j = 0; j < 8; ++j) {
    f32x4 e = *reinterpret_cast<const f32x4*>(ep + (size_t)j * HW);
    f32x4 r = e * s4;
    __builtin_nontemporal_store(r, reinterpret_cast<f32x4*>(op + (size_t)j * HW));
  }
}

extern "C" void kernel_launch(void* const* d_in, const int* in_sizes, int n_in,
                              void* d_out, int out_size, void* d_ws, size_t ws_size,
                              hipStream_t stream) {
  const float* ent    = (const float*)d_in[0];
  const float* oh     = (const float*)d_in[1];
  const float* W_emb  = (const float*)d_in[2];
  const float* b_emb  = (const float*)d_in[3];
  const float* conv_w = (const float*)d_in[4];
  const float* conv_b = (const float*)d_in[5];
  const float* c1w    = (const float*)d_in[6];
  const float* c1b    = (const float*)d_in[7];
  const float* c2w    = (const float*)d_in[8];
  const float* c2b    = (const float*)d_in[9];
  const int*   h1     = (const int*)d_in[10];
  const int*   h2     = (const int*)d_in[11];
  const float* s1     = (const float*)d_in[12];
  const float* s2     = (const float*)d_in[13];

  float* ws  = (float*)d_ws;
  float* sk1 = ws;                         // 32*256 f32
  float* G   = ws + NB * Dq;               // 32*8192 f32
  unsigned short* Abuf = (unsigned short*)(ws + NB * Dq + NB * 8192);  // 32*16*64*8 bf16

  hipLaunchKernelGGL(k_sk1, dim3(NB), dim3(256), 0, stream,
                     oh, W_emb, b_emb, conv_w, conv_b, h1, s1, sk1);
  hipLaunchKernelGGL(k_G, dim3(NB * 32), dim3(256), 0, stream,
                     sk1, c1w, h2, s2, G);
  hipLaunchKernelGGL(k_A, dim3(NB), dim3(256), 0, stream, G, Abuf);
  hipLaunchKernelGGL(k_map, dim3(49, NB), dim3(256), 0, stream,
                     ent, Abuf, c1b, c2w, c2b, (float*)d_out);
  hipLaunchKernelGGL(k_mul, dim3(3136), dim3(256), 0, stream,
                     ent, (const float*)d_out, (float*)d_out);
}

// Round 7
// 80.654 us; speedup vs baseline: 1.7250x; 1.0715x over previous
//
#include <hip/hip_runtime.h>

#define Dq   256
#define ATTR 400
#define HW   3136
#define NB   32

typedef __attribute__((ext_vector_type(8))) short bf16x8;
typedef __attribute__((ext_vector_type(4))) float f32x4;

__device__ __forceinline__ unsigned short f2bf(float f) {
  unsigned int x = __float_as_uint(f);
  return (unsigned short)((x + 0x7FFFu + ((x >> 16) & 1u)) >> 16);
}

// ---------------- Kernel A: per-batch count-sketch vector sk1[b][256] ----------------
__global__ __launch_bounds__(256) void k_sk1(
    const float* __restrict__ oh, const float* __restrict__ W_emb,
    const float* __restrict__ b_emb, const float* __restrict__ conv_w,
    const float* __restrict__ conv_b, const int* __restrict__ h1,
    const float* __restrict__ s1, float* __restrict__ sk1_out) {
  __shared__ float ohs[ATTR];
  __shared__ float ts[Dq];
  __shared__ float sk[Dq];
  const int b = blockIdx.x, tid = threadIdx.x;
  for (int j = tid; j < ATTR; j += 256) ohs[j] = oh[b * ATTR + j];
  sk[tid] = 0.f;
  __syncthreads();
  float acc = b_emb[tid];
  const float* wr = W_emb + tid * ATTR;
  for (int j = 0; j < ATTR; ++j) acc = fmaf(ohs[j], wr[j], acc);
  ts[tid] = acc;
  __syncthreads();
  float a = conv_b[tid];
  const float* cr = conv_w + tid * Dq;
  for (int k = 0; k < Dq; ++k) a = fmaf(ts[k], cr[k], a);
  atomicAdd(&sk[h1[tid]], a * s1[tid]);
  __syncthreads();
  sk1_out[b * Dq + tid] = sk[tid];
}

// ---------------- Kernel B: circular conv + scatter straight into MFMA A-fragment layout ----------------
// Block (b,o). thread tid = c. Writes Abuf[b][frag][lane][j] (bf16) where
// A[m=o][k=c] = G[b][c][o] = s2[c] * T[o,h2[c]]:
//   frag = (o>>4)*8 + (c>>5), lane = (o&15) | (((c>>3)&3)<<4), j = c&7.
__global__ __launch_bounds__(256) void k_G(
    const float* __restrict__ sk1, const float* __restrict__ conv1_w,
    const int* __restrict__ h2, const float* __restrict__ s2,
    unsigned short* __restrict__ Abuf) {
  __shared__ float sks[Dq];
  __shared__ float w1[Dq];
  __shared__ float Tl[Dq];
  const int b = blockIdx.x >> 5, o = blockIdx.x & 31, c = threadIdx.x;
  sks[c] = sk1[b * Dq + c];
  w1[c]  = conv1_w[o * Dq + c];
  __syncthreads();
  float t = 0.f;
  for (int d = 0; d < Dq; ++d) t = fmaf(w1[d], sks[(d - c) & 255], t);
  Tl[c] = t;
  __syncthreads();
  const float g = s2[c] * Tl[h2[c]];
  const int frag = (o >> 4) * 8 + (c >> 5);
  const int lane = (o & 15) | (((c >> 3) & 3) << 4);
  Abuf[(((size_t)b * 16 + frag) * 64 + lane) * 8 + (c & 7)] = f2bf(g);
}

// ---------------- Fused kernel: MFMA gate + sigmoid + feature multiply ----------------
// Block = 4 waves x 64 lanes; wave w owns pixels px0 = bx*64 + w*16 .. +16.
// Phase 1: per-wave MFMA gate (zero LDS traffic), s broadcast via LDS.
// Phase 2: block-wide coalesced multiply-store (64 px x 256 ch), entity L2-hot.
__global__ __launch_bounds__(256, 4) void k_fused(
    const float* __restrict__ ent,            // [B,256,HW]
    const unsigned short* __restrict__ Abuf,  // [B,16,64,8]
    const float* __restrict__ c1b, const float* __restrict__ c2w,
    const float* __restrict__ c2b,
    float* __restrict__ out)                  // map [B,HW] then feat [B,256,HW]
{
  __shared__ float sv[64];
  const int b = blockIdx.y, tid = threadIdx.x;
  const int w = tid >> 6, l = tid & 63;
  const int px0 = blockIdx.x * 64 + w * 16;

  // A-fragments resident: 2 M-tiles x 8 K-steps, 16B/lane each (64 VGPRs)
  bf16x8 A0[8], A1[8];
  const unsigned short* Ab = Abuf + ((size_t)b * 16 * 64 + l) * 8;
#pragma unroll
  for (int ks = 0; ks < 8; ++ks) {
    A0[ks] = *reinterpret_cast<const bf16x8*>(Ab + (size_t)(0 * 8 + ks) * 64 * 8);
    A1[ks] = *reinterpret_cast<const bf16x8*>(Ab + (size_t)(1 * 8 + ks) * 64 * 8);
  }

  f32x4 acc0 = {0.f, 0.f, 0.f, 0.f}, acc1 = {0.f, 0.f, 0.f, 0.f};
  const float* ep = ent + (size_t)b * Dq * HW + px0 + (l & 15);
  const int krow = (l >> 4) * 8;

#pragma unroll
  for (int ks = 0; ks < 8; ++ks) {
    float f[8];
#pragma unroll
    for (int j = 0; j < 8; ++j)
      f[j] = fmaxf(ep[(size_t)(ks * 32 + krow + j) * HW], 0.f);
    bf16x8 bv;
#pragma unroll
    for (int j = 0; j < 8; ++j) bv[j] = (short)f2bf(f[j]);
    acc0 = __builtin_amdgcn_mfma_f32_16x16x32_bf16(A0[ks], bv, acc0, 0, 0, 0);
    acc1 = __builtin_amdgcn_mfma_f32_16x16x32_bf16(A1[ks], bv, acc1, 0, 0, 0);
  }

  // epilogue: C/D layout col(px)=lane&15, row(o)=(lane>>4)*4+reg (+16 for tile1)
  const float4 b1a = reinterpret_cast<const float4*>(c1b)[l >> 4];
  const float4 b1b = reinterpret_cast<const float4*>(c1b)[(l >> 4) + 4];
  const float4 w2a = reinterpret_cast<const float4*>(c2w)[l >> 4];
  const float4 w2b = reinterpret_cast<const float4*>(c2w)[(l >> 4) + 4];
  float z = 0.f;
  z = fmaf(w2a.x, fmaxf(acc0[0] + b1a.x, 0.f), z);
  z = fmaf(w2a.y, fmaxf(acc0[1] + b1a.y, 0.f), z);
  z = fmaf(w2a.z, fmaxf(acc0[2] + b1a.z, 0.f), z);
  z = fmaf(w2a.w, fmaxf(acc0[3] + b1a.w, 0.f), z);
  z = fmaf(w2b.x, fmaxf(acc1[0] + b1b.x, 0.f), z);
  z = fmaf(w2b.y, fmaxf(acc1[1] + b1b.y, 0.f), z);
  z = fmaf(w2b.z, fmaxf(acc1[2] + b1b.z, 0.f), z);
  z = fmaf(w2b.w, fmaxf(acc1[3] + b1b.w, 0.f), z);
  z += __shfl_xor(z, 16);
  z += __shfl_xor(z, 32);
  const float s = 1.f / (1.f + __expf(-(z + c2b[0])));
  if (l < 16) {
    out[(size_t)b * HW + px0 + l] = s;
    sv[w * 16 + l] = s;
  }
  __syncthreads();

  // Phase 2: 64 lanes = 64 consecutive pixels; 4 waves cover 4 channels/iter.
  const float sval = sv[l];
  const size_t basep = (size_t)b * Dq * HW + (size_t)blockIdx.x * 64 + l + (size_t)w * HW;
  const float* ep2 = ent + basep;
  float* fp2 = out + (size_t)NB * HW + basep;
#pragma unroll 8
  for (int cc = 0; cc < 64; ++cc) {
    float v = ep2[(size_t)cc * 4 * HW];
    __builtin_nontemporal_store(sval * v, &fp2[(size_t)cc * 4 * HW]);
  }
}

extern "C" void kernel_launch(void* const* d_in, const int* in_sizes, int n_in,
                              void* d_out, int out_size, void* d_ws, size_t ws_size,
                              hipStream_t stream) {
  const float* ent    = (const float*)d_in[0];
  const float* oh     = (const float*)d_in[1];
  const float* W_emb  = (const float*)d_in[2];
  const float* b_emb  = (const float*)d_in[3];
  const float* conv_w = (const float*)d_in[4];
  const float* conv_b = (const float*)d_in[5];
  const float* c1w    = (const float*)d_in[6];
  const float* c1b    = (const float*)d_in[7];
  const float* c2w    = (const float*)d_in[8];
  const float* c2b    = (const float*)d_in[9];
  const int*   h1     = (const int*)d_in[10];
  const int*   h2     = (const int*)d_in[11];
  const float* s1     = (const float*)d_in[12];
  const float* s2     = (const float*)d_in[13];

  float* ws  = (float*)d_ws;
  float* sk1 = ws;                                        // 32*256 f32
  unsigned short* Abuf = (unsigned short*)(ws + NB * Dq); // 32*16*64*8 bf16

  hipLaunchKernelGGL(k_sk1, dim3(NB), dim3(256), 0, stream,
                     oh, W_emb, b_emb, conv_w, conv_b, h1, s1, sk1);
  hipLaunchKernelGGL(k_G, dim3(NB * 32), dim3(256), 0, stream,
                     sk1, c1w, h2, s2, Abuf);
  hipLaunchKernelGGL(k_fused, dim3(HW / 64, NB), dim3(256), 0, stream,
                     ent, Abuf, c1b, c2w, c2b, (float*)d_out);
}

// Round 8
// 73.316 us; speedup vs baseline: 1.8977x; 1.1001x over previous
//
#include <hip/hip_runtime.h>

#define Dq   256
#define ATTR 400
#define HW   3136
#define NB   32

typedef __attribute__((ext_vector_type(8))) short bf16x8;
typedef __attribute__((ext_vector_type(4))) float f32x4;

__device__ __forceinline__ unsigned short f2bf(float f) {
  unsigned int x = __float_as_uint(f);
  return (unsigned short)((x + 0x7FFFu + ((x >> 16) & 1u)) >> 16);
}

// ---------------- Kernel A: per-batch count-sketch vector sk1[b][256] ----------------
__global__ __launch_bounds__(256) void k_sk1(
    const float* __restrict__ oh, const float* __restrict__ W_emb,
    const float* __restrict__ b_emb, const float* __restrict__ conv_w,
    const float* __restrict__ conv_b, const int* __restrict__ h1,
    const float* __restrict__ s1, float* __restrict__ sk1_out) {
  __shared__ float ohs[ATTR];
  __shared__ float ts[Dq];
  __shared__ float sk[Dq];
  const int b = blockIdx.x, tid = threadIdx.x;
  for (int j = tid; j < ATTR; j += 256) ohs[j] = oh[b * ATTR + j];
  sk[tid] = 0.f;
  __syncthreads();
  float acc = b_emb[tid];
  const float* wr = W_emb + tid * ATTR;
  for (int j = 0; j < ATTR; ++j) acc = fmaf(ohs[j], wr[j], acc);
  ts[tid] = acc;
  __syncthreads();
  float a = conv_b[tid];
  const float* cr = conv_w + tid * Dq;
  for (int k = 0; k < Dq; ++k) a = fmaf(ts[k], cr[k], a);
  atomicAdd(&sk[h1[tid]], a * s1[tid]);
  __syncthreads();
  sk1_out[b * Dq + tid] = sk[tid];
}

// ---------------- Kernel B: circular conv + scatter straight into MFMA A-fragment layout ----------------
// Block (b,o). thread tid = c. Writes Abuf[b][frag][lane][j] (bf16) where
// A[m=o][k=c] = G[b][c][o] = s2[c] * T[o,h2[c]]:
//   frag = (o>>4)*8 + (c>>5), lane = (o&15) | (((c>>3)&3)<<4), j = c&7.
__global__ __launch_bounds__(256) void k_G(
    const float* __restrict__ sk1, const float* __restrict__ conv1_w,
    const int* __restrict__ h2, const float* __restrict__ s2,
    unsigned short* __restrict__ Abuf) {
  __shared__ float sks[Dq];
  __shared__ float w1[Dq];
  __shared__ float Tl[Dq];
  const int b = blockIdx.x >> 5, o = blockIdx.x & 31, c = threadIdx.x;
  sks[c] = sk1[b * Dq + c];
  w1[c]  = conv1_w[o * Dq + c];
  __syncthreads();
  float t = 0.f;
  for (int d = 0; d < Dq; ++d) t = fmaf(w1[d], sks[(d - c) & 255], t);
  Tl[c] = t;
  __syncthreads();
  const float g = s2[c] * Tl[h2[c]];
  const int frag = (o >> 4) * 8 + (c >> 5);
  const int lane = (o & 15) | (((c >> 3) & 3) << 4);
  Abuf[(((size_t)b * 16 + frag) * 64 + lane) * 8 + (c & 7)] = f2bf(g);
}

// ---------------- Fused kernel: load-once MFMA gate + sigmoid + store-once multiply ----------------
// Wave = 16 pixels x 256 channels; lane l owns pixel px0+(l&15), 64 channels
// ch(j) = (j>>3)*32 + (l>>4)*8 + (j&7). All 64 loads issued before any use
// (deep pipeline); entity values stay in e[64] and are reused for the final
// feature store. No LDS, no __syncthreads -> waves fully independent.
__global__ __launch_bounds__(256, 4) void k_fused(
    const float* __restrict__ ent,            // [B,256,HW]
    const unsigned short* __restrict__ Abuf,  // [B,16,64,8]
    const float* __restrict__ c1b, const float* __restrict__ c2w,
    const float* __restrict__ c2b,
    float* __restrict__ out)                  // map [B,HW] then feat [B,256,HW]
{
  const int b = blockIdx.y, tid = threadIdx.x;
  const int w = tid >> 6, l = tid & 63;
  const int px0 = blockIdx.x * 64 + w * 16;
  const int krow = (l >> 4) * 8;

  const float* ep = ent + (size_t)b * Dq * HW + px0 + (l & 15);

  // ---- issue ALL 64 loads up-front ----
  float e[64];
#pragma unroll
  for (int j = 0; j < 64; ++j) {
    const int ch = (j >> 3) * 32 + krow + (j & 7);
    e[j] = ep[(size_t)ch * HW];
  }

  // ---- gate GEMM on MFMA; A-fragments loaded just-in-time (L2-hot) ----
  const unsigned short* Ab = Abuf + ((size_t)b * 16 * 64 + l) * 8;
  f32x4 acc0 = {0.f, 0.f, 0.f, 0.f}, acc1 = {0.f, 0.f, 0.f, 0.f};
#pragma unroll
  for (int ks = 0; ks < 8; ++ks) {
    bf16x8 bv;
#pragma unroll
    for (int j = 0; j < 8; ++j) bv[j] = (short)f2bf(fmaxf(e[ks * 8 + j], 0.f));
    bf16x8 a0 = *reinterpret_cast<const bf16x8*>(Ab + (size_t)(0 * 8 + ks) * 64 * 8);
    bf16x8 a1 = *reinterpret_cast<const bf16x8*>(Ab + (size_t)(1 * 8 + ks) * 64 * 8);
    acc0 = __builtin_amdgcn_mfma_f32_16x16x32_bf16(a0, bv, acc0, 0, 0, 0);
    acc1 = __builtin_amdgcn_mfma_f32_16x16x32_bf16(a1, bv, acc1, 0, 0, 0);
  }

  // epilogue: C/D layout col(px)=lane&15, row(o)=(lane>>4)*4+reg (+16 for tile1)
  const float4 b1a = reinterpret_cast<const float4*>(c1b)[l >> 4];
  const float4 b1b = reinterpret_cast<const float4*>(c1b)[(l >> 4) + 4];
  const float4 w2a = reinterpret_cast<const float4*>(c2w)[l >> 4];
  const float4 w2b = reinterpret_cast<const float4*>(c2w)[(l >> 4) + 4];
  float z = 0.f;
  z = fmaf(w2a.x, fmaxf(acc0[0] + b1a.x, 0.f), z);
  z = fmaf(w2a.y, fmaxf(acc0[1] + b1a.y, 0.f), z);
  z = fmaf(w2a.z, fmaxf(acc0[2] + b1a.z, 0.f), z);
  z = fmaf(w2a.w, fmaxf(acc0[3] + b1a.w, 0.f), z);
  z = fmaf(w2b.x, fmaxf(acc1[0] + b1b.x, 0.f), z);
  z = fmaf(w2b.y, fmaxf(acc1[1] + b1b.y, 0.f), z);
  z = fmaf(w2b.z, fmaxf(acc1[2] + b1b.z, 0.f), z);
  z = fmaf(w2b.w, fmaxf(acc1[3] + b1b.w, 0.f), z);
  // lanes {l&15, +16, +32, +48} sum -> every lane ends with z for ITS pixel
  z += __shfl_xor(z, 16);
  z += __shfl_xor(z, 32);
  const float s = 1.f / (1.f + __expf(-(z + c2b[0])));

  if (l < 16) out[(size_t)b * HW + px0 + l] = s;

  // ---- feature store straight from registers: one store per loaded value ----
  float* fp = out + (size_t)NB * HW + (size_t)b * Dq * HW + px0 + (l & 15);
#pragma unroll
  for (int j = 0; j < 64; ++j) {
    const int ch = (j >> 3) * 32 + krow + (j & 7);
    __builtin_nontemporal_store(s * e[j], &fp[(size_t)ch * HW]);
  }
}

extern "C" void kernel_launch(void* const* d_in, const int* in_sizes, int n_in,
                              void* d_out, int out_size, void* d_ws, size_t ws_size,
                              hipStream_t stream) {
  const float* ent    = (const float*)d_in[0];
  const float* oh     = (const float*)d_in[1];
  const float* W_emb  = (const float*)d_in[2];
  const float* b_emb  = (const float*)d_in[3];
  const float* conv_w = (const float*)d_in[4];
  const float* conv_b = (const float*)d_in[5];
  const float* c1w    = (const float*)d_in[6];
  const float* c1b    = (const float*)d_in[7];
  const float* c2w    = (const float*)d_in[8];
  const float* c2b    = (const float*)d_in[9];
  const int*   h1     = (const int*)d_in[10];
  const int*   h2     = (const int*)d_in[11];
  const float* s1     = (const float*)d_in[12];
  const float* s2     = (const float*)d_in[13];

  float* ws  = (float*)d_ws;
  float* sk1 = ws;                                        // 32*256 f32
  unsigned short* Abuf = (unsigned short*)(ws + NB * Dq); // 32*16*64*8 bf16

  hipLaunchKernelGGL(k_sk1, dim3(NB), dim3(256), 0, stream,
                     oh, W_emb, b_emb, conv_w, conv_b, h1, s1, sk1);
  hipLaunchKernelGGL(k_G, dim3(NB * 32), dim3(256), 0, stream,
                     sk1, c1w, h2, s2, Abuf);
  hipLaunchKernelGGL(k_fused, dim3(HW / 64, NB), dim3(256), 0, stream,
                     ent, Abuf, c1b, c2w, c2b, (float*)d_out);
}

// Round 9
// 66.397 us; speedup vs baseline: 2.0954x; 1.1042x over previous
//
#include <hip/hip_runtime.h>

#define Dq   256
#define ATTR 400
#define HW   3136
#define NB   32

typedef __attribute__((ext_vector_type(8))) short bf16x8;
typedef __attribute__((ext_vector_type(4))) float f32x4;

__device__ __forceinline__ unsigned short f2bf(float f) {
  unsigned int x = __float_as_uint(f);
  return (unsigned short)((x + 0x7FFFu + ((x >> 16) & 1u)) >> 16);
}

// ---------------- Kernel A: per-batch count-sketch vector sk1[b][256] ----------------
__global__ __launch_bounds__(256) void k_sk1(
    const float* __restrict__ oh, const float* __restrict__ W_emb,
    const float* __restrict__ b_emb, const float* __restrict__ conv_w,
    const float* __restrict__ conv_b, const int* __restrict__ h1,
    const float* __restrict__ s1, float* __restrict__ sk1_out) {
  __shared__ float ohs[ATTR];
  __shared__ float ts[Dq];
  __shared__ float sk[Dq];
  const int b = blockIdx.x, tid = threadIdx.x;
  for (int j = tid; j < ATTR; j += 256) ohs[j] = oh[b * ATTR + j];
  sk[tid] = 0.f;
  __syncthreads();
  float acc = b_emb[tid];
  const float* wr = W_emb + tid * ATTR;
  for (int j = 0; j < ATTR; ++j) acc = fmaf(ohs[j], wr[j], acc);
  ts[tid] = acc;
  __syncthreads();
  float a = conv_b[tid];
  const float* cr = conv_w + tid * Dq;
  for (int k = 0; k < Dq; ++k) a = fmaf(ts[k], cr[k], a);
  atomicAdd(&sk[h1[tid]], a * s1[tid]);
  __syncthreads();
  sk1_out[b * Dq + tid] = sk[tid];
}

// ---------------- Kernel B: circular conv + scatter straight into MFMA A-fragment layout ----------------
// Block (b,o). thread tid = c. Writes Abuf[b][frag][lane][j] (bf16) where
// A[m=o][k=c] = G[b][c][o] = s2[c] * T[o,h2[c]]:
//   frag = (o>>4)*8 + (c>>5), lane = (o&15) | (((c>>3)&3)<<4), j = c&7.
__global__ __launch_bounds__(256) void k_G(
    const float* __restrict__ sk1, const float* __restrict__ conv1_w,
    const int* __restrict__ h2, const float* __restrict__ s2,
    unsigned short* __restrict__ Abuf) {
  __shared__ float sks[Dq];
  __shared__ float w1[Dq];
  __shared__ float Tl[Dq];
  const int b = blockIdx.x >> 5, o = blockIdx.x & 31, c = threadIdx.x;
  sks[c] = sk1[b * Dq + c];
  w1[c]  = conv1_w[o * Dq + c];
  __syncthreads();
  float t = 0.f;
  for (int d = 0; d < Dq; ++d) t = fmaf(w1[d], sks[(d - c) & 255], t);
  Tl[c] = t;
  __syncthreads();
  const float g = s2[c] * Tl[h2[c]];
  const int frag = (o >> 4) * 8 + (c >> 5);
  const int lane = (o & 15) | (((c >> 3) & 3) << 4);
  Abuf[(((size_t)b * 16 + frag) * 64 + lane) * 8 + (c & 7)] = f2bf(g);
}

// ---------------- Fused kernel: load-once MFMA gate + sigmoid + store-once multiply ----------------
// Wave = 16 pixels x 256 channels; lane l owns pixel px0+(l&15), 64 channels
// ch(j) = (j>>3)*32 + (l>>4)*8 + (j&7). All 64 loads issued up-front and
// PINNED live in VGPRs (asm "+v") so the compiler can neither re-batch the
// loads (kills MLP) nor re-load for the store phase. Plain (cached) stores
// let L2 write-combine the 64B wave-chunks into full lines.
__global__ __launch_bounds__(256, 4) void k_fused(
    const float* __restrict__ ent,            // [B,256,HW]
    const unsigned short* __restrict__ Abuf,  // [B,16,64,8]
    const float* __restrict__ c1b, const float* __restrict__ c2w,
    const float* __restrict__ c2b,
    float* __restrict__ out)                  // map [B,HW] then feat [B,256,HW]
{
  const int b = blockIdx.y, tid = threadIdx.x;
  const int w = tid >> 6, l = tid & 63;
  const int px0 = blockIdx.x * 64 + w * 16;
  const int krow = (l >> 4) * 8;

  const float* ep = ent + (size_t)b * Dq * HW + px0 + (l & 15);

  // ---- issue ALL 64 loads up-front ----
  float e[64];
#pragma unroll
  for (int j = 0; j < 64; ++j) {
    const int ch = (j >> 3) * 32 + krow + (j & 7);
    e[j] = ep[(size_t)ch * HW];
  }
  // pin: forces all loads complete here and values to stay in VGPRs
#pragma unroll
  for (int j = 0; j < 64; j += 8) {
    asm volatile("" : "+v"(e[j + 0]), "+v"(e[j + 1]), "+v"(e[j + 2]), "+v"(e[j + 3]),
                      "+v"(e[j + 4]), "+v"(e[j + 5]), "+v"(e[j + 6]), "+v"(e[j + 7]));
  }

  // ---- gate GEMM on MFMA; A-fragments loaded just-in-time (L2-hot) ----
  const unsigned short* Ab = Abuf + ((size_t)b * 16 * 64 + l) * 8;
  f32x4 acc0 = {0.f, 0.f, 0.f, 0.f}, acc1 = {0.f, 0.f, 0.f, 0.f};
#pragma unroll
  for (int ks = 0; ks < 8; ++ks) {
    bf16x8 bv;
#pragma unroll
    for (int j = 0; j < 8; ++j) bv[j] = (short)f2bf(fmaxf(e[ks * 8 + j], 0.f));
    bf16x8 a0 = *reinterpret_cast<const bf16x8*>(Ab + (size_t)(0 * 8 + ks) * 64 * 8);
    bf16x8 a1 = *reinterpret_cast<const bf16x8*>(Ab + (size_t)(1 * 8 + ks) * 64 * 8);
    acc0 = __builtin_amdgcn_mfma_f32_16x16x32_bf16(a0, bv, acc0, 0, 0, 0);
    acc1 = __builtin_amdgcn_mfma_f32_16x16x32_bf16(a1, bv, acc1, 0, 0, 0);
  }

  // epilogue: C/D layout col(px)=lane&15, row(o)=(lane>>4)*4+reg (+16 for tile1)
  const float4 b1a = reinterpret_cast<const float4*>(c1b)[l >> 4];
  const float4 b1b = reinterpret_cast<const float4*>(c1b)[(l >> 4) + 4];
  const float4 w2a = reinterpret_cast<const float4*>(c2w)[l >> 4];
  const float4 w2b = reinterpret_cast<const float4*>(c2w)[(l >> 4) + 4];
  float z = 0.f;
  z = fmaf(w2a.x, fmaxf(acc0[0] + b1a.x, 0.f), z);
  z = fmaf(w2a.y, fmaxf(acc0[1] + b1a.y, 0.f), z);
  z = fmaf(w2a.z, fmaxf(acc0[2] + b1a.z, 0.f), z);
  z = fmaf(w2a.w, fmaxf(acc0[3] + b1a.w, 0.f), z);
  z = fmaf(w2b.x, fmaxf(acc1[0] + b1b.x, 0.f), z);
  z = fmaf(w2b.y, fmaxf(acc1[1] + b1b.y, 0.f), z);
  z = fmaf(w2b.z, fmaxf(acc1[2] + b1b.z, 0.f), z);
  z = fmaf(w2b.w, fmaxf(acc1[3] + b1b.w, 0.f), z);
  // lanes {l&15, +16, +32, +48} sum -> every lane ends with z for ITS pixel
  z += __shfl_xor(z, 16);
  z += __shfl_xor(z, 32);
  const float s = 1.f / (1.f + __expf(-(z + c2b[0])));

  if (l < 16) out[(size_t)b * HW + px0 + l] = s;

  // ---- feature store straight from registers (cached: L2 merges 64B chunks) ----
  float* fp = out + (size_t)NB * HW + (size_t)b * Dq * HW + px0 + (l & 15);
#pragma unroll
  for (int j = 0; j < 64; ++j) {
    const int ch = (j >> 3) * 32 + krow + (j & 7);
    fp[(size_t)ch * HW] = s * e[j];
  }
}

extern "C" void kernel_launch(void* const* d_in, const int* in_sizes, int n_in,
                              void* d_out, int out_size, void* d_ws, size_t ws_size,
                              hipStream_t stream) {
  const float* ent    = (const float*)d_in[0];
  const float* oh     = (const float*)d_in[1];
  const float* W_emb  = (const float*)d_in[2];
  const float* b_emb  = (const float*)d_in[3];
  const float* conv_w = (const float*)d_in[4];
  const float* conv_b = (const float*)d_in[5];
  const float* c1w    = (const float*)d_in[6];
  const float* c1b    = (const float*)d_in[7];
  const float* c2w    = (const float*)d_in[8];
  const float* c2b    = (const float*)d_in[9];
  const int*   h1     = (const int*)d_in[10];
  const int*   h2     = (const int*)d_in[11];
  const float* s1     = (const float*)d_in[12];
  const float* s2     = (const float*)d_in[13];

  float* ws  = (float*)d_ws;
  float* sk1 = ws;                                        // 32*256 f32
  unsigned short* Abuf = (unsigned short*)(ws + NB * Dq); // 32*16*64*8 bf16

  hipLaunchKernelGGL(k_sk1, dim3(NB), dim3(256), 0, stream,
                     oh, W_emb, b_emb, conv_w, conv_b, h1, s1, sk1);
  hipLaunchKernelGGL(k_G, dim3(NB * 32), dim3(256), 0, stream,
                     sk1, c1w, h2, s2, Abuf);
  hipLaunchKernelGGL(k_fused, dim3(HW / 64, NB), dim3(256), 0, stream,
                     ent, Abuf, c1b, c2w, c2b, (float*)d_out);
}